// Round 1
// baseline (794.760 us; speedup 1.0000x reference)
//
#include <hip/hip_runtime.h>
#include <math.h>

#define N_Q 20000
#define KK 48
#define CC 64
#define FFD 256
#define OUTD 64

// ---------------------------------------------------------------------------
// Transpose all weight matrices into ws so per-thread row reads are coalesced.
// Layout in tw (floats):
//   [0,4096)      WqT  [j*64+r]  = Wq[r,j]      (in_w rows 0..63)
//   [4096,8192)   WkT                            (in_w rows 64..127)
//   [8192,12288)  WvT                            (in_w rows 128..191)
//   [12288,16384) WoT  [j*64+r]  = out_w[r,j]
//   [16384,32768) L1T  [j*256+f] = lin1_w[f,j]
//   [32768,49152) L2T  [f*64+c]  = lin2_w[c,f]
//   [49152,53248) OlT  [j*64+o]  = outl_w[o,j]
// ---------------------------------------------------------------------------
__global__ void transpose_weights(const float* __restrict__ in_w,
                                  const float* __restrict__ out_w,
                                  const float* __restrict__ lin1_w,
                                  const float* __restrict__ lin2_w,
                                  const float* __restrict__ outl_w,
                                  float* __restrict__ tw)
{
    int t = blockIdx.x * blockDim.x + threadIdx.x;
    if (t < 12288) {
        int sub = t >> 12, rem = t & 4095, r = rem >> 6, j = rem & 63;
        tw[(sub << 12) + j * 64 + r] = in_w[t];
    } else if (t < 16384) {
        int idx = t - 12288, r = idx >> 6, j = idx & 63;
        tw[12288 + j * 64 + r] = out_w[idx];
    } else if (t < 32768) {
        int idx = t - 16384, r = idx >> 6, j = idx & 63;   // 256 rows, 64 cols
        tw[16384 + j * 256 + r] = lin1_w[idx];
    } else if (t < 49152) {
        int idx = t - 32768, r = idx >> 8, jf = idx & 255; // 64 rows, 256 cols
        tw[32768 + jf * 64 + r] = lin2_w[idx];
    } else if (t < 53248) {
        int idx = t - 49152, r = idx >> 6, j = idx & 63;
        tw[49152 + j * 64 + r] = outl_w[idx];
    }
}

// ---------------------------------------------------------------------------
// One wave per query. Thread = channel c. Wk/Wv rows live in 128 VGPRs.
// ---------------------------------------------------------------------------
__global__ __launch_bounds__(64) void attn_kernel(
    const float* __restrict__ vfeat,
    const float* __restrict__ vcoord,
    const float* __restrict__ qcoord,
    const int*   __restrict__ kidx,
    const float* __restrict__ q_w,
    const float* __restrict__ q_b,
    const float* __restrict__ kpos_w,
    const float* __restrict__ kpos_b,
    const float* __restrict__ in_b,
    const float* __restrict__ out_b,
    const float* __restrict__ lin1_b,
    const float* __restrict__ lin2_b,
    const float* __restrict__ tw,
    float* __restrict__ y_out,
    float* __restrict__ sum1,
    float* __restrict__ sumsq1)
{
    const int n = blockIdx.x;
    const int c = threadIdx.x;
    const int h = c >> 4;
    const int l = c & 15;

    const float* WqT = tw;
    const float* WkT = tw + 4096;
    const float* WvT = tw + 8192;
    const float* WoT = tw + 12288;
    const float* L1T = tw + 16384;
    const float* L2T = tw + 32768;

    __shared__ __align__(16) float sh_qf[CC];
    __shared__ __align__(16) float sh_kf[CC];
    __shared__ __align__(16) float sh_v[KK][CC];
    __shared__ __align__(16) float sh_sc[4][KK];
    __shared__ __align__(16) float sh_ctx[CC];
    __shared__ __align__(16) float sh_att[CC];
    __shared__ __align__(16) float sh_hid[FFD];

    const float qc0 = qcoord[n * 3 + 0];
    const float qc1 = qcoord[n * 3 + 1];
    const float qc2 = qcoord[n * 3 + 2];

    // query positional projection (relu)
    float qf = fmaf(q_w[c * 3 + 2], qc2, q_b[c]);
    qf = fmaf(q_w[c * 3 + 1], qc1, qf);
    qf = fmaf(q_w[c * 3 + 0], qc0, qf);
    qf = fmaxf(qf, 0.0f);
    sh_qf[c] = qf;

    // Wk/Wv rows into registers (coalesced via transposed layout)
    float wkr[CC], wvr[CC];
    #pragma unroll
    for (int j = 0; j < CC; ++j) {
        wkr[j] = WkT[j * 64 + c];
        wvr[j] = WvT[j * 64 + c];
    }
    const float bk = in_b[64 + c];
    const float bv = in_b[128 + c];
    const float kw0 = kpos_w[c * 3 + 0], kw1 = kpos_w[c * 3 + 1],
                kw2 = kpos_w[c * 3 + 2], kpb = kpos_b[c];

    __syncthreads();

    // q = (Wq @ q_feat + bq) / sqrt(16)
    float qreg = in_b[c];
    #pragma unroll
    for (int j = 0; j < CC; ++j)
        qreg = fmaf(sh_qf[j], WqT[j * 64 + c], qreg);
    qreg *= 0.25f;

    // ----- key loop -----
    for (int k = 0; k < KK; ++k) {
        int idx = kidx[n * KK + k];
        int safe = (idx < 0) ? 0 : idx;
        float f  = vfeat[safe * 64 + c];
        float r0 = vcoord[safe * 3 + 0] - qc0;
        float r1 = vcoord[safe * 3 + 1] - qc1;
        float r2 = vcoord[safe * 3 + 2] - qc2;
        float pe = fmaf(kw2, r2, kpb);
        pe = fmaf(kw1, r1, pe);
        pe = fmaf(kw0, r0, pe);
        pe = fmaxf(pe, 0.0f);

        __syncthreads();               // WAR on sh_kf
        sh_kf[c] = f + pe;
        __syncthreads();

        float aK = bk, aV = bv;
        #pragma unroll
        for (int j = 0; j < CC; j += 4) {
            float4 a = *(const float4*)&sh_kf[j];
            aK = fmaf(a.x, wkr[j + 0], aK);
            aK = fmaf(a.y, wkr[j + 1], aK);
            aK = fmaf(a.z, wkr[j + 2], aK);
            aK = fmaf(a.w, wkr[j + 3], aK);
            aV = fmaf(a.x, wvr[j + 0], aV);
            aV = fmaf(a.y, wvr[j + 1], aV);
            aV = fmaf(a.z, wvr[j + 2], aV);
            aV = fmaf(a.w, wvr[j + 3], aV);
        }
        sh_v[k][c] = aV;

        // score[h,k] = sum over 16 lanes of q*k
        float p = qreg * aK;
        #pragma unroll
        for (int off = 8; off >= 1; off >>= 1) p += __shfl_xor(p, off, 16);
        if (l == 0) sh_sc[h][k] = (idx < 0) ? -INFINITY : p;
    }
    __syncthreads();

    // ----- softmax (lane l of head h handles k = l, l+16, l+32) -----
    {
        float s0 = sh_sc[h][l], s1 = sh_sc[h][l + 16], s2 = sh_sc[h][l + 32];
        float mx = fmaxf(s0, fmaxf(s1, s2));
        #pragma unroll
        for (int off = 8; off >= 1; off >>= 1) mx = fmaxf(mx, __shfl_xor(mx, off, 16));
        float e0 = __expf(s0 - mx), e1 = __expf(s1 - mx), e2 = __expf(s2 - mx);
        float es = e0 + e1 + e2;
        #pragma unroll
        for (int off = 8; off >= 1; off >>= 1) es += __shfl_xor(es, off, 16);
        float r = 1.0f / es;
        sh_sc[h][l]      = e0 * r;
        sh_sc[h][l + 16] = e1 * r;
        sh_sc[h][l + 32] = e2 * r;
    }
    __syncthreads();

    // ----- ctx = attn @ V -----
    float ctx = 0.0f;
    #pragma unroll 8
    for (int k = 0; k < KK; ++k)
        ctx = fmaf(sh_sc[h][k], sh_v[k][c], ctx);
    sh_ctx[c] = ctx;
    __syncthreads();

    // ----- output projection -----
    float att = out_b[c];
    #pragma unroll 8
    for (int j = 0; j < CC; ++j)
        att = fmaf(sh_ctx[j], WoT[j * 64 + c], att);
    sh_att[c] = att;
    __syncthreads();

    // ----- FFN: thread c computes hidden f = c, c+64, c+128, c+192 -----
    float h0 = lin1_b[c], h1 = lin1_b[c + 64], h2 = lin1_b[c + 128], h3 = lin1_b[c + 192];
    #pragma unroll 8
    for (int j = 0; j < CC; ++j) {
        float a = sh_att[j];
        h0 = fmaf(a, L1T[j * 256 + c + 0  ], h0);
        h1 = fmaf(a, L1T[j * 256 + c + 64 ], h1);
        h2 = fmaf(a, L1T[j * 256 + c + 128], h2);
        h3 = fmaf(a, L1T[j * 256 + c + 192], h3);
    }
    sh_hid[c + 0  ] = fmaxf(h0, 0.0f);
    sh_hid[c + 64 ] = fmaxf(h1, 0.0f);
    sh_hid[c + 128] = fmaxf(h2, 0.0f);
    sh_hid[c + 192] = fmaxf(h3, 0.0f);
    __syncthreads();

    float y = att + lin2_b[c];
    #pragma unroll 16
    for (int ff = 0; ff < FFD; ++ff)
        y = fmaf(sh_hid[ff], L2T[ff * 64 + c], y);

    y_out[n * 64 + c] = y;
    atomicAdd(&sum1[c], y);
    atomicAdd(&sumsq1[c], y * y);
}

// ---------------------------------------------------------------------------
// Fold BN stats into scale/shift: a = g*rsqrt(var+eps), b' = b - mu*a
// ---------------------------------------------------------------------------
__global__ void bn_stats_kernel(const float* __restrict__ sum,
                                const float* __restrict__ sumsq,
                                const float* __restrict__ g,
                                const float* __restrict__ b,
                                float* __restrict__ a_out,
                                float* __restrict__ b_out)
{
    int c = threadIdx.x;
    const float invN = 1.0f / 20000.0f;
    float mu  = sum[c] * invN;
    float var = fmaf(-mu, mu, sumsq[c] * invN);
    float inv = 1.0f / sqrtf(var + 1e-5f);
    float a = g[c] * inv;
    a_out[c] = a;
    b_out[c] = fmaf(-mu, a, b[c]);
}

// ---------------------------------------------------------------------------
// xn = y*a1+b1 ; z = OutL @ xn + b ; accumulate BN2 stats. 8 rows per block.
// ---------------------------------------------------------------------------
__global__ __launch_bounds__(64) void lin_out_kernel(
    const float* __restrict__ y,
    const float* __restrict__ a1,
    const float* __restrict__ b1,
    const float* __restrict__ outlT,
    const float* __restrict__ outl_b,
    float* __restrict__ z,
    float* __restrict__ sum2,
    float* __restrict__ sumsq2)
{
    int c = threadIdx.x;
    __shared__ __align__(16) float sh_xn[2][CC];
    float w[CC];
    #pragma unroll
    for (int j = 0; j < CC; ++j) w[j] = outlT[j * 64 + c];
    float ob = outl_b[c];
    float ac = a1[c], bc = b1[c];
    float s = 0.0f, ss = 0.0f;
    int base = blockIdx.x * 8;
    for (int r = 0; r < 8; ++r) {
        int n = base + r;
        float yv = y[n * 64 + c];
        float* buf = sh_xn[r & 1];
        __syncthreads();
        buf[c] = fmaf(yv, ac, bc);
        __syncthreads();
        float acc = ob;
        #pragma unroll
        for (int j = 0; j < CC; j += 4) {
            float4 x4 = *(const float4*)&buf[j];
            acc = fmaf(x4.x, w[j + 0], acc);
            acc = fmaf(x4.y, w[j + 1], acc);
            acc = fmaf(x4.z, w[j + 2], acc);
            acc = fmaf(x4.w, w[j + 3], acc);
        }
        z[n * 64 + c] = acc;
        s += acc;
        ss += acc * acc;
    }
    atomicAdd(&sum2[c], s);
    atomicAdd(&sumsq2[c], ss);
}

// ---------------------------------------------------------------------------
// out = relu(z*a2 + b2), in place on d_out, float4 vectorized
// ---------------------------------------------------------------------------
__global__ void final_kernel(float* __restrict__ z,
                             const float* __restrict__ a2,
                             const float* __restrict__ b2)
{
    int i = blockIdx.x * blockDim.x + threadIdx.x;
    if (i < N_Q * OUTD / 4) {
        float4 v = ((float4*)z)[i];
        int o = (i << 2) & 63;
        v.x = fmaxf(fmaf(v.x, a2[o + 0], b2[o + 0]), 0.0f);
        v.y = fmaxf(fmaf(v.y, a2[o + 1], b2[o + 1]), 0.0f);
        v.z = fmaxf(fmaf(v.z, a2[o + 2], b2[o + 2]), 0.0f);
        v.w = fmaxf(fmaf(v.w, a2[o + 3], b2[o + 3]), 0.0f);
        ((float4*)z)[i] = v;
    }
}

extern "C" void kernel_launch(void* const* d_in, const int* in_sizes, int n_in,
                              void* d_out, int out_size, void* d_ws, size_t ws_size,
                              hipStream_t stream)
{
    const float* vfeat  = (const float*)d_in[0];
    const float* vcoord = (const float*)d_in[1];
    const float* qcoord = (const float*)d_in[2];
    const int*   kidx   = (const int*)d_in[3];
    const float* q_w    = (const float*)d_in[4];
    const float* q_b    = (const float*)d_in[5];
    const float* kpos_w = (const float*)d_in[6];
    const float* kpos_b = (const float*)d_in[7];
    const float* in_w   = (const float*)d_in[8];
    const float* in_b   = (const float*)d_in[9];
    const float* out_w  = (const float*)d_in[10];
    const float* out_b  = (const float*)d_in[11];
    const float* lin1_w = (const float*)d_in[12];
    const float* lin1_b = (const float*)d_in[13];
    const float* lin2_w = (const float*)d_in[14];
    const float* lin2_b = (const float*)d_in[15];
    const float* norm_g = (const float*)d_in[16];
    const float* norm_b = (const float*)d_in[17];
    const float* outl_w = (const float*)d_in[18];
    const float* outl_b = (const float*)d_in[19];
    const float* obn_g  = (const float*)d_in[20];
    const float* obn_b  = (const float*)d_in[21];

    float* ws     = (float*)d_ws;
    float* y      = ws;                 // N*64 = 1,280,000 floats
    float* stats  = ws + 1280000;       // 512 floats
    float* tw     = ws + 1280512;       // 53,248 floats
    float* sum1   = stats;
    float* sumsq1 = stats + 64;
    float* a1     = stats + 128;
    float* b1     = stats + 192;
    float* sum2   = stats + 256;
    float* sumsq2 = stats + 320;
    float* a2     = stats + 384;
    float* b2     = stats + 448;
    float* z      = (float*)d_out;

    hipMemsetAsync(stats, 0, 512 * sizeof(float), stream);
    transpose_weights<<<208, 256, 0, stream>>>(in_w, out_w, lin1_w, lin2_w, outl_w, tw);
    attn_kernel<<<N_Q, 64, 0, stream>>>(vfeat, vcoord, qcoord, kidx, q_w, q_b,
                                        kpos_w, kpos_b, in_b, out_b, lin1_b, lin2_b,
                                        tw, y, sum1, sumsq1);
    bn_stats_kernel<<<1, 64, 0, stream>>>(sum1, sumsq1, norm_g, norm_b, a1, b1);
    lin_out_kernel<<<2500, 64, 0, stream>>>(y, a1, b1, tw + 49152, outl_b, z, sum2, sumsq2);
    bn_stats_kernel<<<1, 64, 0, stream>>>(sum2, sumsq2, obn_g, obn_b, a2, b2);
    final_kernel<<<1250, 256, 0, stream>>>(z, a2, b2);
}